// Round 16
// baseline (74.136 us; speedup 1.0000x reference)
//
#include <hip/hip_runtime.h>
#include <math.h>

#define N_ROWS 131072
#define U2_OFF 4096   // floats: swT = ws[0..4095] ([256][16]), U2 = ws[4096..4351] (16x16)
#define ZXST 20       // z-exchange row stride (floats): conflict-free b128 (R6/R8-proven)
#define SINK_OFF (1u << 20)   // sink at ws+4MB (floats)
#define SRC_OFF  (8u << 20)   // diag read region at ws+32MB (floats), cold (fill-evicted)

// ---------------- stage-1 builder: 8-qubit state, 4 amps/lane ----------------
__device__ __forceinline__ void ry8(float v[4], int lane, int bp, float c, float s) {
  if (bp == 0) {
    float n0 = fmaf(s, v[1], c * v[0]);
    float n1 = fmaf(-s, v[0], c * v[1]);
    float n2 = fmaf(s, v[3], c * v[2]);
    float n3 = fmaf(-s, v[2], c * v[3]);
    v[0] = n0; v[1] = n1; v[2] = n2; v[3] = n3;
  } else if (bp == 1) {
    float n0 = fmaf(s, v[2], c * v[0]);
    float n2 = fmaf(-s, v[0], c * v[2]);
    float n1 = fmaf(s, v[3], c * v[1]);
    float n3 = fmaf(-s, v[1], c * v[3]);
    v[0] = n0; v[1] = n1; v[2] = n2; v[3] = n3;
  } else {
    int lm = 1 << (bp - 2);
    float sgn = ((lane >> (bp - 2)) & 1) ? -s : s;
#pragma unroll
    for (int k = 0; k < 4; ++k) {
      float o = __shfl_xor(v[k], lm);
      v[k] = fmaf(sgn, o, c * v[k]);
    }
  }
}

__device__ __forceinline__ void cnot8(float v[4], int lane, int cb, int tb) {
  if (cb >= 2 && tb >= 2) {
    int lm = 1 << (tb - 2);
    bool hc = (lane >> (cb - 2)) & 1;
#pragma unroll
    for (int k = 0; k < 4; ++k) {
      float o = __shfl_xor(v[k], lm);
      v[k] = hc ? o : v[k];
    }
  } else if (cb >= 2) {
    bool hc = (lane >> (cb - 2)) & 1;
    if (tb == 0) {
      float n0 = hc ? v[1] : v[0], n1 = hc ? v[0] : v[1];
      float n2 = hc ? v[3] : v[2], n3 = hc ? v[2] : v[3];
      v[0] = n0; v[1] = n1; v[2] = n2; v[3] = n3;
    } else {
      float n0 = hc ? v[2] : v[0], n2 = hc ? v[0] : v[2];
      float n1 = hc ? v[3] : v[1], n3 = hc ? v[1] : v[3];
      v[0] = n0; v[1] = n1; v[2] = n2; v[3] = n3;
    }
  } else if (tb >= 2) {
    int lm = 1 << (tb - 2);
#pragma unroll
    for (int k = 0; k < 4; ++k) {
      float o = __shfl_xor(v[k], lm);
      if ((k >> cb) & 1) v[k] = o;
    }
  } else {
    if (cb == 0) { float t = v[1]; v[1] = v[3]; v[3] = t; }
    else         { float t = v[2]; v[2] = v[3]; v[3] = t; }
  }
}

// ---------------- stage-2 builder: full 16-dim state in registers ----------------
template <int BP>
__device__ __forceinline__ void ry16t(float* w, float c, float s) {
#pragma unroll
  for (int i = 0; i < 16; ++i) {
    if (((i >> BP) & 1) == 0) {
      const int j = i | (1 << BP);
      float a = w[i], b = w[j];
      w[i] = fmaf(s, b, c * a);
      w[j] = fmaf(-s, a, c * b);
    }
  }
}
__device__ __forceinline__ void ry16(float* w, int bp, float c, float s) {
  switch (bp) {
    case 0: ry16t<0>(w, c, s); break;
    case 1: ry16t<1>(w, c, s); break;
    case 2: ry16t<2>(w, c, s); break;
    default: ry16t<3>(w, c, s); break;
  }
}
template <int CB, int TB>
__device__ __forceinline__ void cnot16t(float* w) {
#pragma unroll
  for (int i = 0; i < 16; ++i) {
    if (((i >> CB) & 1) == 1 && ((i >> TB) & 1) == 0) {
      const int j = i | (1 << TB);
      float t = w[i]; w[i] = w[j]; w[j] = t;
    }
  }
}
__device__ __forceinline__ void cnot16(float* w, int cb, int tb) {
#define CC(a, b) if (cb == a && tb == b) { cnot16t<a, b>(w); return; }
  CC(0,1) CC(0,2) CC(0,3) CC(1,0) CC(1,2) CC(1,3)
  CC(2,0) CC(2,1) CC(2,3) CC(3,0) CC(3,1) CC(3,2)
#undef CC
}

__global__ void build_states_kernel(const float* __restrict__ thc,
                                    const float* __restrict__ th2,
                                    float* __restrict__ ws) {
  const int blk = blockIdx.x;
  const int lane = threadIdx.x;  // 64 threads
  if (blk < 16) {
    const float* th = thc + blk * 72;
    float v[4] = {0.f, 0.f, 0.f, 0.f};
    if (lane == 0) v[0] = 1.f;
    int p = 0;
    for (int m = 0; m < 8; ++m) {
#pragma unroll
      for (int q = 0; q < 8; ++q) {
        float a = 0.5f * th[p + q];
        ry8(v, lane, 7 - q, __cosf(a), __sinf(a));
      }
      p += 8;
#pragma unroll
      for (int q = 0; q < 8; ++q) {
        int tgt = (m % 2 == 0) ? ((q + 1) & 7) : ((q + 7) & 7);
        cnot8(v, lane, 7 - q, 7 - tgt);
      }
    }
#pragma unroll
    for (int q = 0; q < 8; ++q) {
      float a = 0.5f * th[p + q];
      ry8(v, lane, 7 - q, __cosf(a), __sinf(a));
    }
    // TRANSPOSED store: swT[k][c], k = 4*lane + kk, c = blk
#pragma unroll
    for (int kk = 0; kk < 4; ++kk) ws[(4 * lane + kk) * 16 + blk] = v[kk];
  } else {
    float w[16];
#pragma unroll
    for (int j = 0; j < 16; ++j) w[j] = (j == lane) ? 1.f : 0.f;
    int p = 0;
    for (int m = 0; m < 8; ++m) {
#pragma unroll
      for (int q = 0; q < 4; ++q) {
        float a = 0.5f * th2[p + q];
        ry16(w, 3 - q, __cosf(a), __sinf(a));
      }
      p += 4;
#pragma unroll
      for (int q = 0; q < 4; ++q) {
        int tgt = (m % 2 == 0) ? ((q + 1) & 3) : ((q + 3) & 3);
        cnot16(w, 3 - q, 3 - tgt);
      }
    }
#pragma unroll
    for (int q = 0; q < 4; ++q) {
      float a = 0.5f * th2[p + q];
      ry16(w, 3 - q, __cosf(a), __sinf(a));
    }
    if (lane < 16) {
      float* u2 = ws + U2_OFF;
#pragma unroll
      for (int j = 0; j < 16; ++j) u2[lane * 16 + j] = w[j];
    }
  }
}

__device__ __forceinline__ float silu_g(float z) {
  float v = z / (1.f + __expf(-z));
  return isfinite(v) ? v : 0.f;
}

// 16 FMAs: per-lane x element * wave-uniform swT row (s_load -> SGPR operand)
#define FMA16(xe, sp)                                                          \
  {                                                                            \
    const float xe_ = (xe);                                                    \
    const float* __restrict__ s_ = (sp);                                       \
    _Pragma("unroll") for (int c = 0; c < 16; ++c)                             \
        z[c] = fmaf(xe_, s_[c], z[c]);                                         \
  }

// ---------------- main kernel: HIGH OCCUPANCY (32 waves/CU) ----------------
// 2048 blocks x 256 thr, launch_bounds(256,8) -> 8 blocks/CU = 32 waves/CU
// (2x R6's ~13). Block owns 64 rows; lane owns row rb+lane; wave w owns
// k-quarter [64w, 64w+64) -> per-wave scalar footprint 4 KB (all four
// quarters = whole 16KB K$, each quarter shared by 8 waves/CU). x via
// per-lane direct float4 loads with 1-deep prefetch (R6-proven). z-exchange
// via R8-proven padded LDS layout; wave 0 runs the folded epilogue.
__global__ __launch_bounds__(256, 8) void hadamard_main_kernel(
    const float* __restrict__ x, const float* __restrict__ ws,
    float* __restrict__ out) {
  __shared__ __align__(16) float zx[3][64][ZXST];  // 15.4 KB

  const int t = threadIdx.x;
  const int lane = t & 63;
  const int w = __builtin_amdgcn_readfirstlane(t >> 6);  // wave id = k-quarter
  const int row = blockIdx.x * 64 + lane;

  const float* __restrict__ swT = ws;  // [256][16]
  const float4* __restrict__ xr =
      (const float4*)(x + (size_t)row * 256 + w * 64);  // 16 float4s

  float z[16];
#pragma unroll
  for (int c = 0; c < 16; ++c) z[c] = 0.f;

  float4 A0 = xr[0], A1 = xr[1], A2 = xr[2], A3 = xr[3];

#pragma unroll 1
  for (int kb = 0; kb < 4; ++kb) {
    const int pk = (kb < 3 ? kb + 1 : 3) * 4;
    float4 B0 = xr[pk], B1 = xr[pk + 1], B2 = xr[pk + 2], B3 = xr[pk + 3];

    const float* __restrict__ sb = swT + (size_t)(w * 64 + kb * 16) * 16;
    FMA16(A0.x, sb + 0)   FMA16(A0.y, sb + 16)  FMA16(A0.z, sb + 32)  FMA16(A0.w, sb + 48)
    FMA16(A1.x, sb + 64)  FMA16(A1.y, sb + 80)  FMA16(A1.z, sb + 96)  FMA16(A1.w, sb + 112)
    FMA16(A2.x, sb + 128) FMA16(A2.y, sb + 144) FMA16(A2.z, sb + 160) FMA16(A2.w, sb + 176)
    FMA16(A3.x, sb + 192) FMA16(A3.y, sb + 208) FMA16(A3.z, sb + 224) FMA16(A3.w, sb + 240)

    A0 = B0; A1 = B1; A2 = B2; A3 = B3;
  }

  // ---- combine k-quarter partials via LDS (R8-proven layout) ----
  if (w > 0) {
    float4* zp = (float4*)&zx[w - 1][lane][0];
    zp[0] = make_float4(z[0], z[1], z[2], z[3]);
    zp[1] = make_float4(z[4], z[5], z[6], z[7]);
    zp[2] = make_float4(z[8], z[9], z[10], z[11]);
    zp[3] = make_float4(z[12], z[13], z[14], z[15]);
  }
  __syncthreads();

  if (w == 0) {
#pragma unroll
    for (int p = 0; p < 3; ++p) {
      const float4* zp = (const float4*)&zx[p][lane][0];
      const float4 a0 = zp[0], a1 = zp[1], a2 = zp[2], a3 = zp[3];
      z[0] += a0.x;  z[1] += a0.y;  z[2] += a0.z;  z[3] += a0.w;
      z[4] += a1.x;  z[5] += a1.y;  z[6] += a1.z;  z[7] += a1.w;
      z[8] += a2.x;  z[9] += a2.y;  z[10] += a2.z; z[11] += a2.w;
      z[12] += a3.x; z[13] += a3.y; z[14] += a3.z; z[15] += a3.w;
    }

    // ---------------- per-lane epilogue (row = blockIdx.x*64 + lane) --------
    float f[16];
#pragma unroll
    for (int c = 0; c < 16; ++c) f[c] = silu_g(z[c]);

    // T = f @ U2 (unnormalized; U2 orthogonal => scales cancel in P)
    const float* __restrict__ u2 = ws + U2_OFF;
    float T[16];
#pragma unroll
    for (int j = 0; j < 16; ++j) T[j] = 0.f;
#pragma unroll
    for (int c = 0; c < 16; ++c) {
      const float fc = f[c];
#pragma unroll
      for (int j = 0; j < 16; ++j) T[j] = fmaf(fc, u2[c * 16 + j], T[j]);
    }

    // e[t] = T[t]^2 + T[t+8]^2 ; P = e / sum(e)
    float e[8], es = 0.f;
#pragma unroll
    for (int tt = 0; tt < 8; ++tt) {
      e[tt] = fmaf(T[tt], T[tt], T[tt + 8] * T[tt + 8]);
      es += e[tt];
    }
    const float rinv = 1.f / fmaxf(es, 1e-35f);

    float P[8], lp[8];
#pragma unroll
    for (int tt = 0; tt < 8; ++tt) {
      P[tt] = e[tt] * rinv;
      lp[tt] = __logf(fmaxf(P[tt], 1e-12f));
    }

    float4* o0 = (float4*)(out + (size_t)row * 8);
    o0[0] = make_float4(lp[0], lp[1], lp[2], lp[3]);
    o0[1] = make_float4(lp[4], lp[5], lp[6], lp[7]);
    float4* o1 = (float4*)(out + (size_t)N_ROWS * 8 + (size_t)row * 8);
    o1[0] = make_float4(P[0], P[1], P[2], P[3]);
    o1[1] = make_float4(P[4], P[5], P[6], P[7]);
  }
}

// ---------------- diag: pure cold-read bandwidth reference ----------------
// Streams 134 MB from a cold (fill-evicted) ws region with perfectly
// coalesced float4 loads at full occupancy. Its hbm_gbps is the read
// ceiling this harness state permits (rule #10: external-style reference).
__global__ __launch_bounds__(256, 8) void diag_readbw(
    const float* __restrict__ src, float* __restrict__ sink) {
  const size_t i = (size_t)blockIdx.x * 256 + threadIdx.x;  // 524288 threads
  const float4* __restrict__ s = (const float4*)src;
  float acc = 0.f;
#pragma unroll
  for (int j = 0; j < 16; ++j) {
    const float4 v = s[(size_t)j * 524288 + i];
    acc += (v.x + v.y) + (v.z + v.w);
  }
  sink[i] = acc;
}

extern "C" void kernel_launch(void* const* d_in, const int* in_sizes, int n_in,
                              void* d_out, int out_size, void* d_ws, size_t ws_size,
                              hipStream_t stream) {
  const float* x = (const float*)d_in[0];
  const float* thc = (const float*)d_in[1];
  const float* th2 = (const float*)d_in[2];
  float* out = (float*)d_out;
  float* ws = (float*)d_ws;

  build_states_kernel<<<17, 64, 0, stream>>>(thc, th2, ws);
  hadamard_main_kernel<<<N_ROWS / 64, 256, 0, stream>>>(x, ws, out);
  diag_readbw<<<2048, 256, 0, stream>>>(ws + SRC_OFF, ws + SINK_OFF);
}

// Round 17
// 41.476 us; speedup vs baseline: 1.7874x; 1.7874x over previous
//
#include <hip/hip_runtime.h>
#include <math.h>

#define N_ROWS 131072
#define U2_OFF 4096   // floats: swT = ws[0..4095] ([256][16]), U2 = ws[4096..4351] (16x16)

// ---------------- stage-1 builder: 8-qubit state, 4 amps/lane ----------------
__device__ __forceinline__ void ry8(float v[4], int lane, int bp, float c, float s) {
  if (bp == 0) {
    float n0 = fmaf(s, v[1], c * v[0]);
    float n1 = fmaf(-s, v[0], c * v[1]);
    float n2 = fmaf(s, v[3], c * v[2]);
    float n3 = fmaf(-s, v[2], c * v[3]);
    v[0] = n0; v[1] = n1; v[2] = n2; v[3] = n3;
  } else if (bp == 1) {
    float n0 = fmaf(s, v[2], c * v[0]);
    float n2 = fmaf(-s, v[0], c * v[2]);
    float n1 = fmaf(s, v[3], c * v[1]);
    float n3 = fmaf(-s, v[1], c * v[3]);
    v[0] = n0; v[1] = n1; v[2] = n2; v[3] = n3;
  } else {
    int lm = 1 << (bp - 2);
    float sgn = ((lane >> (bp - 2)) & 1) ? -s : s;
#pragma unroll
    for (int k = 0; k < 4; ++k) {
      float o = __shfl_xor(v[k], lm);
      v[k] = fmaf(sgn, o, c * v[k]);
    }
  }
}

__device__ __forceinline__ void cnot8(float v[4], int lane, int cb, int tb) {
  if (cb >= 2 && tb >= 2) {
    int lm = 1 << (tb - 2);
    bool hc = (lane >> (cb - 2)) & 1;
#pragma unroll
    for (int k = 0; k < 4; ++k) {
      float o = __shfl_xor(v[k], lm);
      v[k] = hc ? o : v[k];
    }
  } else if (cb >= 2) {
    bool hc = (lane >> (cb - 2)) & 1;
    if (tb == 0) {
      float n0 = hc ? v[1] : v[0], n1 = hc ? v[0] : v[1];
      float n2 = hc ? v[3] : v[2], n3 = hc ? v[2] : v[3];
      v[0] = n0; v[1] = n1; v[2] = n2; v[3] = n3;
    } else {
      float n0 = hc ? v[2] : v[0], n2 = hc ? v[0] : v[2];
      float n1 = hc ? v[3] : v[1], n3 = hc ? v[1] : v[3];
      v[0] = n0; v[1] = n1; v[2] = n2; v[3] = n3;
    }
  } else if (tb >= 2) {
    int lm = 1 << (tb - 2);
#pragma unroll
    for (int k = 0; k < 4; ++k) {
      float o = __shfl_xor(v[k], lm);
      if ((k >> cb) & 1) v[k] = o;
    }
  } else {
    if (cb == 0) { float t = v[1]; v[1] = v[3]; v[3] = t; }
    else         { float t = v[2]; v[2] = v[3]; v[3] = t; }
  }
}

// ---------------- stage-2 builder: full 16-dim state in registers ----------------
template <int BP>
__device__ __forceinline__ void ry16t(float* w, float c, float s) {
#pragma unroll
  for (int i = 0; i < 16; ++i) {
    if (((i >> BP) & 1) == 0) {
      const int j = i | (1 << BP);
      float a = w[i], b = w[j];
      w[i] = fmaf(s, b, c * a);
      w[j] = fmaf(-s, a, c * b);
    }
  }
}
__device__ __forceinline__ void ry16(float* w, int bp, float c, float s) {
  switch (bp) {
    case 0: ry16t<0>(w, c, s); break;
    case 1: ry16t<1>(w, c, s); break;
    case 2: ry16t<2>(w, c, s); break;
    default: ry16t<3>(w, c, s); break;
  }
}
template <int CB, int TB>
__device__ __forceinline__ void cnot16t(float* w) {
#pragma unroll
  for (int i = 0; i < 16; ++i) {
    if (((i >> CB) & 1) == 1 && ((i >> TB) & 1) == 0) {
      const int j = i | (1 << TB);
      float t = w[i]; w[i] = w[j]; w[j] = t;
    }
  }
}
__device__ __forceinline__ void cnot16(float* w, int cb, int tb) {
#define CC(a, b) if (cb == a && tb == b) { cnot16t<a, b>(w); return; }
  CC(0,1) CC(0,2) CC(0,3) CC(1,0) CC(1,2) CC(1,3)
  CC(2,0) CC(2,1) CC(2,3) CC(3,0) CC(3,1) CC(3,2)
#undef CC
}

__global__ void build_states_kernel(const float* __restrict__ thc,
                                    const float* __restrict__ th2,
                                    float* __restrict__ ws) {
  const int blk = blockIdx.x;
  const int lane = threadIdx.x;  // 64 threads
  if (blk < 16) {
    const float* th = thc + blk * 72;
    float v[4] = {0.f, 0.f, 0.f, 0.f};
    if (lane == 0) v[0] = 1.f;
    int p = 0;
    for (int m = 0; m < 8; ++m) {
#pragma unroll
      for (int q = 0; q < 8; ++q) {
        float a = 0.5f * th[p + q];
        ry8(v, lane, 7 - q, __cosf(a), __sinf(a));
      }
      p += 8;
#pragma unroll
      for (int q = 0; q < 8; ++q) {
        int tgt = (m % 2 == 0) ? ((q + 1) & 7) : ((q + 7) & 7);
        cnot8(v, lane, 7 - q, 7 - tgt);
      }
    }
#pragma unroll
    for (int q = 0; q < 8; ++q) {
      float a = 0.5f * th[p + q];
      ry8(v, lane, 7 - q, __cosf(a), __sinf(a));
    }
    // TRANSPOSED store: swT[k][c], k = 4*lane + kk, c = blk
#pragma unroll
    for (int kk = 0; kk < 4; ++kk) ws[(4 * lane + kk) * 16 + blk] = v[kk];
  } else {
    float w[16];
#pragma unroll
    for (int j = 0; j < 16; ++j) w[j] = (j == lane) ? 1.f : 0.f;
    int p = 0;
    for (int m = 0; m < 8; ++m) {
#pragma unroll
      for (int q = 0; q < 4; ++q) {
        float a = 0.5f * th2[p + q];
        ry16(w, 3 - q, __cosf(a), __sinf(a));
      }
      p += 4;
#pragma unroll
      for (int q = 0; q < 4; ++q) {
        int tgt = (m % 2 == 0) ? ((q + 1) & 3) : ((q + 3) & 3);
        cnot16(w, 3 - q, 3 - tgt);
      }
    }
#pragma unroll
    for (int q = 0; q < 4; ++q) {
      float a = 0.5f * th2[p + q];
      ry16(w, 3 - q, __cosf(a), __sinf(a));
    }
    if (lane < 16) {
      float* u2 = ws + U2_OFF;
#pragma unroll
      for (int j = 0; j < 16; ++j) u2[lane * 16 + j] = w[j];
    }
  }
}

__device__ __forceinline__ float silu_g(float z) {
  float v = z / (1.f + __expf(-z));
  return isfinite(v) ? v : 0.f;
}

// async global -> LDS, 16 B per lane (wave-uniform LDS base + lane*16)
__device__ __forceinline__ void stage16(const float* g, float* l) {
  __builtin_amdgcn_global_load_lds(
      (const __attribute__((address_space(1))) void*)g,
      (__attribute__((address_space(3))) void*)l, 16, 0, 0);
}

// 16 FMAs into a named accumulator: per-lane x elem * wave-uniform swT row
#define FMA16A(zz, xe, sp)                                                     \
  {                                                                            \
    const float xe_ = (xe);                                                    \
    const float* __restrict__ s_ = (sp);                                       \
    _Pragma("unroll") for (int c = 0; c < 16; ++c)                             \
        zz[c] = fmaf(xe_, s_[c], zz[c]);                                       \
  }

// ---------------- main kernel (R15 = best measured, 41.7 us total) ----------
// Block = 256 thr = 4 waves, 128 rows; lane owns rows (lane, lane+64), wave w
// owns k-quarter. x staged via global_load_lds into a 4-slot ring of
// [128 rows x 16 k] chunks; counted vmcnt(4/2/0) + one s_barrier per chunk.
// Quad-rotation swizzle: phys quad p=(q+row)&3 (source-side pre-swizzle,
// read-side un-rotate) -> ds_read_b128 <=2-way (free). sw via wave-uniform
// s_load -> SGPR operands. z-exchange aliased over staging LDS; waves 0-1
// run the per-lane epilogue (normalizations folded out: U2 orthogonal, final
// P-norm scale-invariant). Bound by the cold-read concurrency ceiling
// (~3.4 TB/s effective): main ~38 us vs 21 us ideal-HBM floor.
__global__ __launch_bounds__(256, 4) void hadamard_main_kernel(
    const float* __restrict__ x, const float* __restrict__ ws,
    float* __restrict__ out) {
  __shared__ __align__(16) float xs[4][128][16];  // 32 KB ring (4 x 8 KB)

  const int t = threadIdx.x;
  const int lane = t & 63;
  const int w = __builtin_amdgcn_readfirstlane(t >> 6);  // wave id = k-quarter
  const int rb = blockIdx.x * 128;

  const float* __restrict__ swT = ws;  // [256][16]

  const int rl0 = 32 * w + (lane >> 2);
  const int q0 = ((lane & 3) - rl0) & 3;   // same for rl0+16 (16%4==0)
  const float* g0 = x + (size_t)(rb + rl0) * 256 + q0 * 4;
  const float* g1 = x + (size_t)(rb + rl0 + 16) * 256 + q0 * 4;

#define ISSUE(ck)                                                              \
  {                                                                            \
    const int sl_ = (ck) & 3;                                                  \
    stage16(g0 + (ck) * 16, &xs[sl_][32 * w][0]);                              \
    stage16(g1 + (ck) * 16, &xs[sl_][32 * w + 16][0]);                         \
  }

  float z0[16], z1[16];
#pragma unroll
  for (int c = 0; c < 16; ++c) { z0[c] = 0.f; z1[c] = 0.f; }

  // prologue: 3 chunks (6 loads) in flight
  ISSUE(0) ISSUE(1) ISSUE(2)

  const int p4 = ((w + lane) & 3) * 4;

#pragma unroll 1
  for (int ck = 0; ck < 16; ++ck) {
    if (ck < 14)       asm volatile("s_waitcnt vmcnt(4)" ::: "memory");
    else if (ck == 14) asm volatile("s_waitcnt vmcnt(2)" ::: "memory");
    else               asm volatile("s_waitcnt vmcnt(0)" ::: "memory");
    __builtin_amdgcn_s_barrier();  // all waves' chunk-ck DMA now visible

    const int sl = ck & 3;
    const float4 xa = *(const float4*)&xs[sl][lane][p4];
    const float4 xb = *(const float4*)&xs[sl][64 + lane][p4];

    const float* __restrict__ sb = swT + (size_t)(ck * 16 + w * 4) * 16;
    FMA16A(z0, xa.x, sb + 0)  FMA16A(z0, xa.y, sb + 16)
    FMA16A(z0, xa.z, sb + 32) FMA16A(z0, xa.w, sb + 48)
    FMA16A(z1, xb.x, sb + 0)  FMA16A(z1, xb.y, sb + 16)
    FMA16A(z1, xb.z, sb + 32) FMA16A(z1, xb.w, sb + 48)

    if (ck < 13) ISSUE(ck + 3)  // slot (ck+3)&3 freed by this iter's barrier
  }

  __syncthreads();  // staging fully consumed; alias xs as z-exchange

  // ---- exchange k-quarter partials: zx[4 quarters][128 rows][16 ch] = 32 KB
  float* zx = &xs[0][0][0];
  {
    float4* zp = (float4*)&zx[((size_t)w * 128 + lane) * 16];
    zp[0] = make_float4(z0[0], z0[1], z0[2], z0[3]);
    zp[1] = make_float4(z0[4], z0[5], z0[6], z0[7]);
    zp[2] = make_float4(z0[8], z0[9], z0[10], z0[11]);
    zp[3] = make_float4(z0[12], z0[13], z0[14], z0[15]);
    float4* zq = (float4*)&zx[((size_t)w * 128 + 64 + lane) * 16];
    zq[0] = make_float4(z1[0], z1[1], z1[2], z1[3]);
    zq[1] = make_float4(z1[4], z1[5], z1[6], z1[7]);
    zq[2] = make_float4(z1[8], z1[9], z1[10], z1[11]);
    zq[3] = make_float4(z1[12], z1[13], z1[14], z1[15]);
  }
  __syncthreads();

  if (w < 2) {
    const int rloc = w * 64 + lane;  // local row 0..127
    float z[16];
#pragma unroll
    for (int c = 0; c < 16; ++c) z[c] = 0.f;
#pragma unroll
    for (int p = 0; p < 4; ++p) {
      const float4* zp = (const float4*)&zx[((size_t)p * 128 + rloc) * 16];
      const float4 a0 = zp[0], a1 = zp[1], a2 = zp[2], a3 = zp[3];
      z[0] += a0.x;  z[1] += a0.y;  z[2] += a0.z;  z[3] += a0.w;
      z[4] += a1.x;  z[5] += a1.y;  z[6] += a1.z;  z[7] += a1.w;
      z[8] += a2.x;  z[9] += a2.y;  z[10] += a2.z; z[11] += a2.w;
      z[12] += a3.x; z[13] += a3.y; z[14] += a3.z; z[15] += a3.w;
    }

    // ---------------- per-lane epilogue (row = rb + rloc) ----------------
    float f[16];
#pragma unroll
    for (int c = 0; c < 16; ++c) f[c] = silu_g(z[c]);

    // T = f @ U2 (unnormalized; U2 orthogonal => scales cancel in P)
    const float* __restrict__ u2 = ws + U2_OFF;
    float T[16];
#pragma unroll
    for (int j = 0; j < 16; ++j) T[j] = 0.f;
#pragma unroll
    for (int c = 0; c < 16; ++c) {
      const float fc = f[c];
#pragma unroll
      for (int j = 0; j < 16; ++j) T[j] = fmaf(fc, u2[c * 16 + j], T[j]);
    }

    // e[t] = T[t]^2 + T[t+8]^2 ; P = e / sum(e)
    float e[8], es = 0.f;
#pragma unroll
    for (int tt = 0; tt < 8; ++tt) {
      e[tt] = fmaf(T[tt], T[tt], T[tt + 8] * T[tt + 8]);
      es += e[tt];
    }
    const float rinv = 1.f / fmaxf(es, 1e-35f);

    float P[8], lp[8];
#pragma unroll
    for (int tt = 0; tt < 8; ++tt) {
      P[tt] = e[tt] * rinv;
      lp[tt] = __logf(fmaxf(P[tt], 1e-12f));
    }

    const int row = rb + rloc;
    float4* o0 = (float4*)(out + (size_t)row * 8);
    o0[0] = make_float4(lp[0], lp[1], lp[2], lp[3]);
    o0[1] = make_float4(lp[4], lp[5], lp[6], lp[7]);
    float4* o1 = (float4*)(out + (size_t)N_ROWS * 8 + (size_t)row * 8);
    o1[0] = make_float4(P[0], P[1], P[2], P[3]);
    o1[1] = make_float4(P[4], P[5], P[6], P[7]);
  }
#undef ISSUE
}

extern "C" void kernel_launch(void* const* d_in, const int* in_sizes, int n_in,
                              void* d_out, int out_size, void* d_ws, size_t ws_size,
                              hipStream_t stream) {
  const float* x = (const float*)d_in[0];
  const float* thc = (const float*)d_in[1];
  const float* th2 = (const float*)d_in[2];
  float* out = (float*)d_out;
  float* ws = (float*)d_ws;

  build_states_kernel<<<17, 64, 0, stream>>>(thc, th2, ws);
  hadamard_main_kernel<<<N_ROWS / 128, 256, 0, stream>>>(x, ws, out);
}